// Round 1
// baseline (98.356 us; speedup 1.0000x reference)
//
#include <hip/hip_runtime.h>
#include <hip/hip_bf16.h>

typedef float  f32x4  __attribute__((ext_vector_type(4)));
typedef short  s16x8  __attribute__((ext_vector_type(8)));
typedef unsigned short u16x8 __attribute__((ext_vector_type(8)));

#define T_  512
#define D_  512
#define BTD 4194304   // 16*512*512

static __device__ __forceinline__ unsigned short f2bf(float f) {
  unsigned u = __builtin_bit_cast(unsigned, f);
  u += 0x7fffu + ((u >> 16) & 1u);
  return (unsigned short)(u >> 16);
}

static __device__ __forceinline__ void gload_lds16(const void* g, void* l) {
  __builtin_amdgcn_global_load_lds(
      (__attribute__((address_space(1))) void*)(g),
      (__attribute__((address_space(3))) void*)(l),
      16, 0, 0);
}

// ---------------------------------------------------------------------------
// Shared 128x128-tile bt-GEMM mainloop: C += A[M,K] * B[N,K]^T, bf16 MFMA.
// 256 threads = 4 waves as 2x2 of 64x64. BK=32.
// LDS layout per tile: [ks=k/8][128 rows][8 bf16] -> chunk c (1KB) = (ks=c>>1,
// rows (c&1)*64 + lane). ds_read_b128 per fragment, ~2-way bank alias (free).
// ---------------------------------------------------------------------------
__device__ __forceinline__ void gemm_mainloop(
    const unsigned short* __restrict__ A,
    const unsigned short* __restrict__ B,
    int lda, int ldb, int ksteps,
    unsigned short* ldsA, unsigned short* ldsB,
    f32x4 acc[4][4])
{
  const int tid  = threadIdx.x;
  const int lane = tid & 63;
  const int wave = tid >> 6;
  const int wr = wave >> 1, wc = wave & 1;

  const int c0 = wave, c1 = wave + 4;
  const int ks0 = c0 >> 1, r00 = (c0 & 1) * 64;
  const int ks1 = c1 >> 1, r01 = (c1 & 1) * 64;

  const char* ldsAc = (const char*)ldsA;
  const char* ldsBc = (const char*)ldsB;
  const int offA = (lane >> 4) * 2048 + (wr * 64 + (lane & 15)) * 16;
  const int offB = (lane >> 4) * 2048 + (wc * 64 + (lane & 15)) * 16;

  for (int kt = 0; kt < ksteps; ++kt) {
    const unsigned short* Ak = A + kt * 32;
    const unsigned short* Bk = B + kt * 32;
    gload_lds16(Ak + (size_t)(r00 + lane) * lda + ks0 * 8, ldsA + c0 * 512);
    gload_lds16(Ak + (size_t)(r01 + lane) * lda + ks1 * 8, ldsA + c1 * 512);
    gload_lds16(Bk + (size_t)(r00 + lane) * ldb + ks0 * 8, ldsB + c0 * 512);
    gload_lds16(Bk + (size_t)(r01 + lane) * ldb + ks1 * 8, ldsB + c1 * 512);
    __syncthreads();
    s16x8 af[4], bfr[4];
#pragma unroll
    for (int mi = 0; mi < 4; ++mi)
      af[mi] = *(const s16x8*)(ldsAc + offA + mi * 256);
#pragma unroll
    for (int ni = 0; ni < 4; ++ni)
      bfr[ni] = *(const s16x8*)(ldsBc + offB + ni * 256);
#pragma unroll
    for (int mi = 0; mi < 4; ++mi)
#pragma unroll
      for (int ni = 0; ni < 4; ++ni)
        acc[mi][ni] = __builtin_amdgcn_mfma_f32_16x16x32_bf16(
            af[mi], bfr[ni], acc[mi][ni], 0, 0, 0);
    __syncthreads();
  }
}

#define ZERO_ACC(acc)                                        \
  _Pragma("unroll") for (int za = 0; za < 4; ++za)           \
  _Pragma("unroll") for (int zb = 0; zb < 4; ++zb)           \
      acc[za][zb] = (f32x4){0.f, 0.f, 0.f, 0.f};

// ---------------------------------------------------------------------------
__global__ __launch_bounds__(256) void rope_table(float* __restrict__ cosT,
                                                  float* __restrict__ sinT) {
  int idx = blockIdx.x * 256 + threadIdx.x;   // 512*256 entries
  int t = idx >> 8;
  int i = idx & 255;
  // theta = 10000^(-2i/512) = exp(-ln(10000) * 2i/512)
  float theta = expf(-9.210340371976184f * (float)(2 * i) * (1.0f / 512.0f));
  float ang = (float)(t + 1) * theta;
  float s, c;
  sincosf(ang, &s, &c);
  cosT[idx] = c;
  sinT[idx] = s;
}

__global__ __launch_bounds__(256) void conv_bf16(const float* __restrict__ in,
                                                 unsigned short* __restrict__ out,
                                                 int n) {
  int idx = (blockIdx.x * 256 + threadIdx.x) * 8;
  if (idx >= n) return;
  f32x4 a = *(const f32x4*)(in + idx);
  f32x4 b = *(const f32x4*)(in + idx + 4);
  u16x8 o;
  o[0] = f2bf(a[0]); o[1] = f2bf(a[1]); o[2] = f2bf(a[2]); o[3] = f2bf(a[3]);
  o[4] = f2bf(b[0]); o[5] = f2bf(b[1]); o[6] = f2bf(b[2]); o[7] = f2bf(b[3]);
  *(u16x8*)(out + idx) = o;
}

// GEMM1: [8192,512]x[1024,512]^T + bias; cols<512 -> q_bf16, cols>=512 -> RoPE(k)
__global__ __launch_bounds__(256) void gemm_qk(
    const unsigned short* __restrict__ xb, const unsigned short* __restrict__ Wb,
    const float* __restrict__ bias, const float* __restrict__ cosT,
    const float* __restrict__ sinT, unsigned short* __restrict__ qb,
    unsigned short* __restrict__ kb) {
  __shared__ __align__(16) unsigned short ldsA[4096];
  __shared__ __align__(16) unsigned short ldsB[4096];
  const int bm = blockIdx.x, bn = blockIdx.y;
  f32x4 acc[4][4];
  ZERO_ACC(acc);
  gemm_mainloop(xb + (size_t)bm * 128 * 512, Wb + (size_t)bn * 128 * 512,
                512, 512, 16, ldsA, ldsB, acc);
  const int lane = threadIdx.x & 63, wave = threadIdx.x >> 6;
  const int wr = wave >> 1, wc = wave & 1;
  const int rowbase = bm * 128 + wr * 64 + ((lane >> 4) << 2);
  const int colbase = bn * 128 + wc * 64 + (lane & 15);
  const bool isK = (bn >= 4);
#pragma unroll
  for (int ni = 0; ni < 4; ++ni) {
    const int col = colbase + ni * 16;
    const float bv = bias[col];
#pragma unroll
    for (int mi = 0; mi < 4; ++mi) {
#pragma unroll
      for (int r = 0; r < 4; ++r) {
        const int m = rowbase + mi * 16 + r;
        float v = acc[mi][ni][r] + bv;
        if (!isK) {
          qb[(size_t)m * 512 + col] = f2bf(v);
        } else {
          // column pair (2i,2i+1) lives in lanes (l, l^1): exchange via shfl
          float p = __shfl_xor(v, 1);
          const int d = col - 512;
          const int t = m & 511;
          const float c = cosT[t * 256 + (d >> 1)];
          const float s = sinT[t * 256 + (d >> 1)];
          // even d: k[2i]*cos + k[2i+1]*sin ; odd d: -k[2i]*sin + k[2i+1]*cos
          float o = (d & 1) ? (v * c - p * s) : (v * c + p * s);
          kb[(size_t)m * 512 + d] = f2bf(o);
        }
      }
    }
  }
}

// 32x32 tiled bf16 transpose per batch: krot[b][t][d] -> krotT[b][d][t]
__global__ void transpose_bf(const unsigned short* __restrict__ in,
                             unsigned short* __restrict__ out) {
  __shared__ unsigned short tile[32][33];
  const int b = blockIdx.z;
  const int t0 = blockIdx.x * 32, d0 = blockIdx.y * 32;
  const int x = threadIdx.x, y = threadIdx.y;
  const unsigned short* src = in + (size_t)b * 262144;
  unsigned short* dst = out + (size_t)b * 262144;
#pragma unroll
  for (int r = 0; r < 32; r += 8)
    tile[y + r][x] = src[(size_t)(t0 + y + r) * 512 + d0 + x];
  __syncthreads();
#pragma unroll
  for (int r = 0; r < 32; r += 8)
    dst[(size_t)(d0 + y + r) * 512 + t0 + x] = tile[x][y + r];
}

// GEMM2: S[b][i][j] = q[i,:]*krot[j,:] * scale ; only lower-triangular tiles
__global__ __launch_bounds__(256) void gemm_scores(
    const unsigned short* __restrict__ qb, const unsigned short* __restrict__ kb,
    float* __restrict__ S) {
  __shared__ __align__(16) unsigned short ldsA[4096];
  __shared__ __align__(16) unsigned short ldsB[4096];
  const int b = blockIdx.y;
  int idx = blockIdx.x, ti = 0;          // triangular tile enumeration (10 tiles)
  while (idx > ti) { idx -= ti + 1; ++ti; }
  const int tj = idx;
  f32x4 acc[4][4];
  ZERO_ACC(acc);
  gemm_mainloop(qb + (size_t)b * 262144 + (size_t)ti * 128 * 512,
                kb + (size_t)b * 262144 + (size_t)tj * 128 * 512,
                512, 512, 16, ldsA, ldsB, acc);
  const int lane = threadIdx.x & 63, wave = threadIdx.x >> 6;
  const int wr = wave >> 1, wc = wave & 1;
  const int rowbase = ti * 128 + wr * 64 + ((lane >> 4) << 2);
  const int colbase = tj * 128 + wc * 64 + (lane & 15);
  float* Sb = S + (size_t)b * 262144;
  const float scale = 0.044194173824159216f;   // 1/sqrt(512)
#pragma unroll
  for (int mi = 0; mi < 4; ++mi)
#pragma unroll
    for (int ni = 0; ni < 4; ++ni)
#pragma unroll
      for (int r = 0; r < 4; ++r)
        Sb[(size_t)(rowbase + mi * 16 + r) * 512 + colbase + ni * 16] =
            acc[mi][ni][r] * scale;
}

// wave-per-row causal softmax; writes bf16 P (zeros for j>i)
__global__ __launch_bounds__(256) void softmax_causal(
    const float* __restrict__ S, unsigned short* __restrict__ P) {
  const int row = blockIdx.x * 4 + (threadIdx.x >> 6);   // 0..8191
  const int lane = threadIdx.x & 63;
  const int i = row & (T_ - 1);
  const float* sr = S + (size_t)row * T_;
  const int j0 = lane * 8;
  f32x4 v0 = *(const f32x4*)(sr + j0);
  f32x4 v1 = *(const f32x4*)(sr + j0 + 4);
  float v[8] = {v0[0], v0[1], v0[2], v0[3], v1[0], v1[1], v1[2], v1[3]};
  float m = -3.0e38f;
#pragma unroll
  for (int j = 0; j < 8; ++j)
    if (j0 + j <= i) m = fmaxf(m, v[j]);
#pragma unroll
  for (int off = 32; off; off >>= 1) m = fmaxf(m, __shfl_xor(m, off));
  float e[8];
  float sum = 0.f;
#pragma unroll
  for (int j = 0; j < 8; ++j) {
    e[j] = (j0 + j <= i) ? __expf(v[j] - m) : 0.f;
    sum += e[j];
  }
#pragma unroll
  for (int off = 32; off; off >>= 1) sum += __shfl_xor(sum, off);
  const float inv = 1.0f / sum;
  u16x8 o;
#pragma unroll
  for (int j = 0; j < 8; ++j) o[j] = f2bf(e[j] * inv);
  *(u16x8*)(P + (size_t)row * T_ + j0) = o;
}

// GEMM3: y[b][i][d] = sum_j P[i,j] * krotT[d,j]; k-loop clipped at diagonal
__global__ __launch_bounds__(256) void gemm_pv(
    const unsigned short* __restrict__ Pb, const unsigned short* __restrict__ kT,
    float* __restrict__ Y) {
  __shared__ __align__(16) unsigned short ldsA[4096];
  __shared__ __align__(16) unsigned short ldsB[4096];
  const int b = blockIdx.y;
  const int ti = blockIdx.x >> 2, td = blockIdx.x & 3;
  f32x4 acc[4][4];
  ZERO_ACC(acc);
  gemm_mainloop(Pb + (size_t)b * 262144 + (size_t)ti * 128 * 512,
                kT + (size_t)b * 262144 + (size_t)td * 128 * 512,
                512, 512, (ti + 1) * 4, ldsA, ldsB, acc);
  const int lane = threadIdx.x & 63, wave = threadIdx.x >> 6;
  const int wr = wave >> 1, wc = wave & 1;
  const int rowbase = ti * 128 + wr * 64 + ((lane >> 4) << 2);
  const int colbase = td * 128 + wc * 64 + (lane & 15);
  float* Yb = Y + (size_t)b * 262144;
#pragma unroll
  for (int mi = 0; mi < 4; ++mi)
#pragma unroll
    for (int ni = 0; ni < 4; ++ni)
#pragma unroll
      for (int r = 0; r < 4; ++r)
        Yb[(size_t)(rowbase + mi * 16 + r) * 512 + colbase + ni * 16] =
            acc[mi][ni][r];
}

// ---------------------------------------------------------------------------
extern "C" void kernel_launch(void* const* d_in, const int* in_sizes, int n_in,
                              void* d_out, int out_size, void* d_ws, size_t ws_size,
                              hipStream_t stream) {
  (void)in_sizes; (void)n_in; (void)out_size; (void)ws_size;
  const float* x    = (const float*)d_in[0];   // [16,512,512]
  const float* W    = (const float*)d_in[1];   // [1536,512]
  const float* bias = (const float*)d_in[2];   // [1536]
  float* out = (float*)d_out;                  // [16,512,512]
  char* ws = (char*)d_ws;

  float* cosT            = (float*)(ws);                    // 512*256 f32
  float* sinT            = (float*)(ws + 524288);
  unsigned short* xb     = (unsigned short*)(ws + 1048576); // [8192,512] bf16
  unsigned short* Wb     = (unsigned short*)(ws + 9437184); // [1024,512] bf16
  unsigned short* qb     = (unsigned short*)(ws + 10485760);// [16,512,512] bf16
  unsigned short* kb     = (unsigned short*)(ws + 18874368);// krot
  unsigned short* kTb    = (unsigned short*)(ws + 27262976);// krot^T
  float* scores          = (float*)(ws + 35651584);         // [16,512,512] f32
  unsigned short* Pb     = (unsigned short*)(ws + 52428864);// [16,512,512] bf16

  rope_table<<<512, 256, 0, stream>>>(cosT, sinT);
  conv_bf16<<<2048, 256, 0, stream>>>(x, xb, BTD);
  conv_bf16<<<256, 256, 0, stream>>>(W, Wb, 1024 * 512);
  gemm_qk<<<dim3(64, 8), 256, 0, stream>>>(xb, Wb, bias, cosT, sinT, qb, kb);
  transpose_bf<<<dim3(16, 16, 16), dim3(32, 8), 0, stream>>>(kb, kTb);
  gemm_scores<<<dim3(10, 16), 256, 0, stream>>>(qb, kb, scores);
  softmax_causal<<<2048, 256, 0, stream>>>(scores, Pb);
  gemm_pv<<<dim3(16, 16), 256, 0, stream>>>(Pb, kTb, out);
}